// Round 1
// baseline (124.053 us; speedup 1.0000x reference)
//
#include <hip/hip_runtime.h>

// GraphPairClassifier v14: 250 blocks x 50 pairs x 512 threads (8 waves =
//   2 waves/SIMD). R13 analysis: v13_mega absent from rocprof top-5 (<41us);
//   per-CU LDS A-read traffic (16 waves x full-A = 4.3 MB/block ~ 33k cyc)
//   exceeded the MFMA pipe (25k cyc). v14 halves A-traffic by halving waves
//   (NT doubles: per-CU MFMA + B-L2 unchanged) and switches in-place sA to
//   ping-pong buffers (sB0/sB1, 133 KB) -> 1 barrier/layer instead of 2.
//   Same accumulation order as v13 => bitwise-identical outputs.
// Dtypes: device inputs FP32 (bf16-quantized values => fp16 weights exact);
//   output FP32. absmax 3.9e-3 stable R6-R13.

typedef _Float16 half8 __attribute__((ext_vector_type(8)));
typedef float floatx4 __attribute__((ext_vector_type(4)));

// -------- weight prep: fp32 [K,N] row-major -> fp16 16x16x32-fragment order -
// fragment f: lane=f&63, rem=f>>6, nt=rem%(N/16), kb=rem/(N/16);
//   n = nt*16+(lane&15), k = kb*32+(lane>>4)*8+j, j=0..7.
// One thread per fragment: 8 strided reads, one contiguous 16B write.
struct PrepArgsV14 { const float* in[6]; };

__global__ __launch_bounds__(256) void v14_prep(PrepArgsV14 p, _Float16* Bf) {
  const int frags[6] = {8192, 8192, 32768, 16384, 4096, 1024};  // sz/8
  const int lgN[6]   = {8, 8, 9, 8, 7, 6};
  const int off[6]   = {0, 65536, 131072, 393216, 524288, 557056};
  int f = blockIdx.x * 256 + threadIdx.x;
  for (int i = 0; i < 6; ++i) {
    if (f < frags[i]) {
      int N = 1 << lgN[i];
      int lane = f & 63, rem = f >> 6;
      int nt = rem & ((N >> 4) - 1);
      int kb = rem >> (lgN[i] - 4);
      int n = nt * 16 + (lane & 15);
      int k0 = kb * 32 + (lane >> 4) * 8;
      const float* src = p.in[i] + (size_t)k0 * N + n;
      half8 v;
#pragma unroll
      for (int j = 0; j < 8; ++j) v[j] = (_Float16)src[(size_t)j * N];
      *(half8*)(Bf + off[i] + (size_t)f * 8) = v;   // exact: bf16-valued
      return;
    }
    f -= frags[i];
  }
}

// -------- generic ping-pong layer, distance-2 B prefetch --------------------
// MT m-tiles (16 rows from m0), NT n-tiles at n-slot nw, TNT = N/16 total
// n-tiles, KB k-steps of 32. ENC_IN: srcA stride 264 halves; else 520.
// OUT_MODE 0: relu->encode(dst); 1: relu->head concat(dst); 2: relu->head(dst);
//          3: sigmoid->global fp32 (rows r<50 only).
// Ping-pong: no pre-epilogue barrier (dst != src); single barrier at end.
template<int MT, int NT, int TNT, int KB, bool ENC_IN, int OUT_MODE>
__device__ __forceinline__ void layer(
    const _Float16* __restrict__ Bf, const float* __restrict__ bias,
    const _Float16* __restrict__ srcA, _Float16* dstA, float* __restrict__ outg,
    int pair0, int nw, int m0, int lane) {
  const int quad = lane >> 4, lr = lane & 15;
  const int n0 = nw * (NT * 16);
  const int STRIDE = ENC_IN ? 264 : 520;
  const _Float16* bp = Bf + ((size_t)(nw * NT) * 64 + lane) * 8;

  floatx4 acc[MT][NT];
#pragma unroll
  for (int mt = 0; mt < MT; ++mt)
#pragma unroll
    for (int nt = 0; nt < NT; ++nt)
      acc[mt][nt] = (floatx4){0.f, 0.f, 0.f, 0.f};

  half8 bbuf[3][NT];
#pragma unroll
  for (int nt = 0; nt < NT; ++nt) {
    bbuf[0][nt] = *(const half8*)(bp + nt * 512);
    bbuf[1][nt] = *(const half8*)(bp + (size_t)TNT * 512 + nt * 512);
  }

#pragma unroll
  for (int kb = 0; kb < KB; ++kb) {
    const int cur = kb % 3;
    half8 av[MT];
#pragma unroll
    for (int mt = 0; mt < MT; ++mt)
      av[mt] = *(const half8*)(srcA + (m0 + mt * 16 + lr) * STRIDE + kb * 32 + quad * 8);
#pragma unroll
    for (int nt = 0; nt < NT; ++nt)
#pragma unroll
      for (int mt = 0; mt < MT; ++mt)
        acc[mt][nt] = __builtin_amdgcn_mfma_f32_16x16x32_f16(av[mt], bbuf[cur][nt], acc[mt][nt], 0, 0, 0);
    if (kb + 2 < KB) {
      const int nxt = (kb + 2) % 3;
#pragma unroll
      for (int nt = 0; nt < NT; ++nt)
        bbuf[nxt][nt] = *(const half8*)(bp + (size_t)(kb + 2) * (TNT * 512) + nt * 512);
    }
  }

  // epilogue straight after own MFMAs: dst buffer != src buffer (no WAR)
#pragma unroll
  for (int nt = 0; nt < NT; ++nt) {
    int c = n0 + nt * 16 + lr;
    float bv = bias[c];
#pragma unroll
    for (int mt = 0; mt < MT; ++mt) {
#pragma unroll
      for (int reg = 0; reg < 4; ++reg) {
        int r = m0 + mt * 16 + quad * 4 + reg;
        float v = acc[mt][nt][reg] + bv;
        if (OUT_MODE <= 2) {
          v = fmaxf(v, 0.f);
          int a;
          if (OUT_MODE == 0)      a = r * 264 + c;                        // encode
          else if (OUT_MODE == 1) a = (r >> 1) * 520 + (r & 1) * 256 + c; // concat
          else                    a = r * 520 + c;                        // head
          dstA[a] = (_Float16)v;
        } else {
          if (r < 50) outg[(size_t)(pair0 + r) * 64 + c] = 1.0f / (1.0f + expf(-v));
        }
      }
    }
  }
  __syncthreads();
}

// -------- megakernel: 50 pairs (100 side rows, pad 112) per 512-thr block ---
__global__ __launch_bounds__(512, 2) void v14_mega(
    const float* __restrict__ x1, const float* __restrict__ x2,
    const float* __restrict__ W1, const float* __restrict__ b1,
    const _Float16* __restrict__ Bf,
    const float* __restrict__ b2, const float* __restrict__ b3,
    const float* __restrict__ bl1, const float* __restrict__ bl2,
    const float* __restrict__ bl3, const float* __restrict__ bl4,
    float* __restrict__ outg) {
  // ping-pong buffers: encode [112][264]=29568 halves; head [64][520]=33280
  __shared__ _Float16 sB0[33280];
  __shared__ _Float16 sB1[33280];
  __shared__ float sM[112][3];

  int tid = threadIdx.x;
  int wave = tid >> 6, lane = tid & 63;
  int pair0 = blockIdx.x * 50;

  // Phase -1: only stale-read hazard is H1 reading sB0 head rows 56..63
  // (halves 29120..33280; L3 writes head rows only 0..55). Zero that tail.
  for (int i = tid; i < 2080; i += 512) ((float*)sB0)[14560 + i] = 0.f;

  // Phase 0: per-side-row mean of the 4 node coords (100 real rows, 12 pad)
  if (tid < 112) {
    int r = tid;
    float a0 = 0.f, a1 = 0.f, a2 = 0.f;
    if (r < 100) {
      int g = pair0 + (r >> 1);                    // always < 12500
      const float* q = ((r & 1) ? x2 : x1) + (size_t)g * 12;
      a0 = 0.25f * (q[0] + q[3] + q[6] + q[9]);
      a1 = 0.25f * (q[1] + q[4] + q[7] + q[10]);
      a2 = 0.25f * (q[2] + q[5] + q[8] + q[11]);
    }
    sM[r][0] = a0; sM[r][1] = a1; sM[r][2] = a2;
  }
  __syncthreads();

  // Phase 1: L1 (3 -> 256), fp32 VALU, fp16 into sB0 (encode layout, 112 rows)
  {
    int c = tid & 255;
    float w0 = W1[c], w1 = W1[256 + c], w2 = W1[512 + c], bb = b1[c];
    for (int r = (tid >> 8); r < 112; r += 2) {
      float v = fmaxf(sM[r][0] * w0 + sM[r][1] * w1 + sM[r][2] * w2 + bb, 0.f);
      sB0[r * 264 + c] = (_Float16)v;
    }
  }
  __syncthreads();

  // L2: [112x256]@[256x256] relu, sB0->sB1        (8 waves x NT=2, 16 n-tiles)
  layer<7, 2, 16,  8, true,  0>(Bf + 0,      b2,  sB0, sB1, nullptr, pair0, wave, 0, lane);
  // L3: [112x256]@[256x256] relu, sB1->sB0 concat
  layer<7, 2, 16,  8, true,  1>(Bf + 65536,  b3,  sB1, sB0, nullptr, pair0, wave, 0, lane);
  // H1: [64x512]@[512x512] relu, sB0->sB1         (8 waves x NT=4, 32 n-tiles)
  layer<4, 4, 32, 16, false, 2>(Bf + 131072, bl1, sB0, sB1, nullptr, pair0, wave, 0, lane);
  // H2: [64x512]@[512x256] relu, sB1->sB0         (8 waves x NT=2, 16 n-tiles)
  layer<4, 2, 16, 16, false, 2>(Bf + 393216, bl2, sB1, sB0, nullptr, pair0, wave, 0, lane);
  // H3: [64x256]@[256x128] relu, sB0->sB1         (8 waves x NT=1, 8 n-tiles)
  layer<4, 1,  8,  8, false, 2>(Bf + 524288, bl3, sB0, sB1, nullptr, pair0, wave, 0, lane);
  // H4: [64x128]@[128x64] sigmoid -> global       (4 n-slots x 2 m-groups)
  layer<2, 1,  4,  4, false, 3>(Bf + 557056, bl4, sB1, nullptr, outg, pair0,
                                wave & 3, (wave >> 2) * 32, lane);
}

extern "C" void kernel_launch(void* const* d_in, const int* in_sizes, int n_in,
                              void* d_out, int out_size, void* d_ws, size_t ws_size,
                              hipStream_t stream) {
  const float* x1  = (const float*)d_in[0];
  const float* x2  = (const float*)d_in[3];
  const float* W1  = (const float*)d_in[6];
  const float* b1  = (const float*)d_in[7];
  const float* W2  = (const float*)d_in[8];
  const float* b2  = (const float*)d_in[9];
  const float* W3  = (const float*)d_in[10];
  const float* b3  = (const float*)d_in[11];
  const float* Wl1 = (const float*)d_in[12];
  const float* bl1 = (const float*)d_in[13];
  const float* Wl2 = (const float*)d_in[14];
  const float* bl2 = (const float*)d_in[15];
  const float* Wl3 = (const float*)d_in[16];
  const float* bl3 = (const float*)d_in[17];
  const float* Wl4 = (const float*)d_in[18];
  const float* bl4 = (const float*)d_in[19];

  _Float16* Bf = (_Float16*)d_ws;   // 565248 halves = 1.13 MB

  PrepArgsV14 pa;
  pa.in[0] = W2;  pa.in[1] = W3;  pa.in[2] = Wl1;
  pa.in[3] = Wl2; pa.in[4] = Wl3; pa.in[5] = Wl4;

  v14_prep<<<dim3(276), dim3(256), 0, stream>>>(pa, Bf);
  v14_mega<<<dim3(250), dim3(512), 0, stream>>>(x1, x2, W1, b1, Bf,
                                                b2, b3, bl1, bl2, bl3, bl4,
                                                (float*)d_out);
}

// Round 2
// 118.201 us; speedup vs baseline: 1.0495x; 1.0495x over previous
//
#include <hip/hip_runtime.h>

// GraphPairClassifier v15: 250 blocks x 50 pairs x 1024 threads (16 waves =
//   4 waves/SIMD; v14's 8 waves was L2-latency-exposed, re-confirming R12).
//   New vs v13: (a) ping-pong LDS buffers (sB0/sB1) -> 1 barrier/layer,
//   barriers hoisted OUT of the layer template (wave-divergent m-split calls);
//   (b) M-split across waves on the A-heavy layers L2/L3 (Wn=8 x Wm=2,
//   NT=2) and H2 (Wn=8 x Wm=2) -> halves per-CU LDS A-read traffic (the
//   binder at 85 B/cyc ds_read_b128) while keeping 4 waves/SIMD. H1 stays
//   Wn=16 (B=512KB: m-split would make L2-B the binder).
//   Same per-element accumulation order as v13 => bitwise-identical output.
// Dtypes: device inputs FP32 (bf16-quantized values => fp16 weights exact);
//   output FP32. absmax 3.9e-3 stable R6-R14.

typedef _Float16 half8 __attribute__((ext_vector_type(8)));
typedef float floatx4 __attribute__((ext_vector_type(4)));

// -------- weight prep: fp32 [K,N] row-major -> fp16 16x16x32-fragment order -
// fragment f: lane=f&63, rem=f>>6, nt=rem%(N/16), kb=rem/(N/16);
//   n = nt*16+(lane&15), k = kb*32+(lane>>4)*8+j, j=0..7.
// One thread per fragment: 8 strided reads, one contiguous 16B write.
struct PrepArgsV15 { const float* in[6]; };

__global__ __launch_bounds__(256) void v15_prep(PrepArgsV15 p, _Float16* Bf) {
  const int frags[6] = {8192, 8192, 32768, 16384, 4096, 1024};  // sz/8
  const int lgN[6]   = {8, 8, 9, 8, 7, 6};
  const int off[6]   = {0, 65536, 131072, 393216, 524288, 557056};
  int f = blockIdx.x * 256 + threadIdx.x;
  for (int i = 0; i < 6; ++i) {
    if (f < frags[i]) {
      int N = 1 << lgN[i];
      int lane = f & 63, rem = f >> 6;
      int nt = rem & ((N >> 4) - 1);
      int kb = rem >> (lgN[i] - 4);
      int n = nt * 16 + (lane & 15);
      int k0 = kb * 32 + (lane >> 4) * 8;
      const float* src = p.in[i] + (size_t)k0 * N + n;
      half8 v;
#pragma unroll
      for (int j = 0; j < 8; ++j) v[j] = (_Float16)src[(size_t)j * N];
      *(half8*)(Bf + off[i] + (size_t)f * 8) = v;   // exact: bf16-valued
      return;
    }
    f -= frags[i];
  }
}

// -------- generic ping-pong layer, distance-2 B prefetch --------------------
// MT m-tiles (16 rows from m0), NT n-tiles at n-slot nw, TNT = N/16 total
// n-tiles, KB k-steps of 32. ENC_IN: srcA stride 264 halves; else 520.
// OUT_MODE 0: relu->encode(dst); 1: relu->head concat(dst); 2: relu->head(dst);
//          3: sigmoid->global fp32 (rows r<50 only).
// NO trailing barrier here — caller syncs (calls may be wave-divergent).
template<int MT, int NT, int TNT, int KB, bool ENC_IN, int OUT_MODE>
__device__ __forceinline__ void layer(
    const _Float16* __restrict__ Bf, const float* __restrict__ bias,
    const _Float16* __restrict__ srcA, _Float16* dstA, float* __restrict__ outg,
    int pair0, int nw, int m0, int lane) {
  const int quad = lane >> 4, lr = lane & 15;
  const int n0 = nw * (NT * 16);
  const int STRIDE = ENC_IN ? 264 : 520;
  const _Float16* bp = Bf + ((size_t)(nw * NT) * 64 + lane) * 8;

  floatx4 acc[MT][NT];
#pragma unroll
  for (int mt = 0; mt < MT; ++mt)
#pragma unroll
    for (int nt = 0; nt < NT; ++nt)
      acc[mt][nt] = (floatx4){0.f, 0.f, 0.f, 0.f};

  half8 bbuf[3][NT];
#pragma unroll
  for (int nt = 0; nt < NT; ++nt) {
    bbuf[0][nt] = *(const half8*)(bp + nt * 512);
    bbuf[1][nt] = *(const half8*)(bp + (size_t)TNT * 512 + nt * 512);
  }

#pragma unroll
  for (int kb = 0; kb < KB; ++kb) {
    const int cur = kb % 3;
    half8 av[MT];
#pragma unroll
    for (int mt = 0; mt < MT; ++mt)
      av[mt] = *(const half8*)(srcA + (m0 + mt * 16 + lr) * STRIDE + kb * 32 + quad * 8);
#pragma unroll
    for (int nt = 0; nt < NT; ++nt)
#pragma unroll
      for (int mt = 0; mt < MT; ++mt)
        acc[mt][nt] = __builtin_amdgcn_mfma_f32_16x16x32_f16(av[mt], bbuf[cur][nt], acc[mt][nt], 0, 0, 0);
    if (kb + 2 < KB) {
      const int nxt = (kb + 2) % 3;
#pragma unroll
      for (int nt = 0; nt < NT; ++nt)
        bbuf[nxt][nt] = *(const half8*)(bp + (size_t)(kb + 2) * (TNT * 512) + nt * 512);
    }
  }

  // epilogue straight after own MFMAs: dst buffer != src buffer (no WAR)
#pragma unroll
  for (int nt = 0; nt < NT; ++nt) {
    int c = n0 + nt * 16 + lr;
    float bv = bias[c];
#pragma unroll
    for (int mt = 0; mt < MT; ++mt) {
#pragma unroll
      for (int reg = 0; reg < 4; ++reg) {
        int r = m0 + mt * 16 + quad * 4 + reg;
        float v = acc[mt][nt][reg] + bv;
        if (OUT_MODE <= 2) {
          v = fmaxf(v, 0.f);
          int a;
          if (OUT_MODE == 0)      a = r * 264 + c;                        // encode
          else if (OUT_MODE == 1) a = (r >> 1) * 520 + (r & 1) * 256 + c; // concat
          else                    a = r * 520 + c;                        // head
          dstA[a] = (_Float16)v;
        } else {
          if (r < 50) outg[(size_t)(pair0 + r) * 64 + c] = 1.0f / (1.0f + expf(-v));
        }
      }
    }
  }
}

// -------- megakernel: 50 pairs (100 side rows, pad 112) per 1024-thr block --
__global__ __launch_bounds__(1024) void v15_mega(
    const float* __restrict__ x1, const float* __restrict__ x2,
    const float* __restrict__ W1, const float* __restrict__ b1,
    const _Float16* __restrict__ Bf,
    const float* __restrict__ b2, const float* __restrict__ b3,
    const float* __restrict__ bl1, const float* __restrict__ bl2,
    const float* __restrict__ bl3, const float* __restrict__ bl4,
    float* __restrict__ outg) {
  // ping-pong buffers: encode [112][264]=29568 halves; head [64][520]=33280
  __shared__ _Float16 sB0[33280];
  __shared__ _Float16 sB1[33280];
  __shared__ float sM[112][3];

  int tid = threadIdx.x;
  int wave = tid >> 6, lane = tid & 63;
  int pair0 = blockIdx.x * 50;

  // Phase -1: guarantee sB0 is fully finite after L1. L1 writes encode halves
  // [0,29568); H1 later reads head rows 56..63 = halves [29120,33280). Zero
  // the never-written tail [29568,33280) plus overlap (cheap, one pass).
  for (int i = tid; i < 2080; i += 1024) ((float*)sB0)[14560 + i] = 0.f;

  // Phase 0: per-side-row mean of the 4 node coords (100 real rows, 12 pad)
  if (tid < 112) {
    int r = tid;
    float a0 = 0.f, a1 = 0.f, a2 = 0.f;
    if (r < 100) {
      int g = pair0 + (r >> 1);                    // always < 12500
      const float* q = ((r & 1) ? x2 : x1) + (size_t)g * 12;
      a0 = 0.25f * (q[0] + q[3] + q[6] + q[9]);
      a1 = 0.25f * (q[1] + q[4] + q[7] + q[10]);
      a2 = 0.25f * (q[2] + q[5] + q[8] + q[11]);
    }
    sM[r][0] = a0; sM[r][1] = a1; sM[r][2] = a2;
  }
  __syncthreads();

  // Phase 1: L1 (3 -> 256), fp32 VALU, fp16 into sB0 (encode layout, 112 rows)
  {
    int c = tid & 255;
    float w0 = W1[c], w1 = W1[256 + c], w2 = W1[512 + c], bb = b1[c];
    for (int r = (tid >> 8); r < 112; r += 4) {
      float v = fmaxf(sM[r][0] * w0 + sM[r][1] * w1 + sM[r][2] * w2 + bb, 0.f);
      sB0[r * 264 + c] = (_Float16)v;
    }
  }
  __syncthreads();

  // L2: [112x256]@[256x256] relu, sB0->sB1   (Wn=8 x Wm=2: rows 0..63 / 64..111)
  if (wave < 8) layer<4, 2, 16,  8, true,  0>(Bf + 0,      b2,  sB0, sB1, nullptr, pair0, wave,     0,  lane);
  else          layer<3, 2, 16,  8, true,  0>(Bf + 0,      b2,  sB0, sB1, nullptr, pair0, wave - 8, 64, lane);
  __syncthreads();
  // L3: [112x256]@[256x256] relu, sB1->sB0 (concat head layout)
  if (wave < 8) layer<4, 2, 16,  8, true,  1>(Bf + 65536,  b3,  sB1, sB0, nullptr, pair0, wave,     0,  lane);
  else          layer<3, 2, 16,  8, true,  1>(Bf + 65536,  b3,  sB1, sB0, nullptr, pair0, wave - 8, 64, lane);
  __syncthreads();
  // H1: [64x512]@[512x512] relu, sB0->sB1    (Wn=16 x NT=2; B-heavy, no m-split)
  layer<4, 2, 32, 16, false, 2>(Bf + 131072, bl1, sB0, sB1, nullptr, pair0, wave, 0, lane);
  __syncthreads();
  // H2: [64x512]@[512x256] relu, sB1->sB0    (Wn=8 x Wm=2: rows 0..31 / 32..63)
  if (wave < 8) layer<2, 2, 16, 16, false, 2>(Bf + 393216, bl2, sB1, sB0, nullptr, pair0, wave,     0,  lane);
  else          layer<2, 2, 16, 16, false, 2>(Bf + 393216, bl2, sB1, sB0, nullptr, pair0, wave - 8, 32, lane);
  __syncthreads();
  // H3: [64x256]@[256x128] relu, sB0->sB1    (Wn=8 x Wm=2)
  layer<2, 1,  8,  8, false, 2>(Bf + 524288, bl3, sB0, sB1, nullptr, pair0,
                                wave & 7, (wave >> 3) * 32, lane);
  __syncthreads();
  // H4: [64x128]@[128x64] sigmoid -> global  (Wn=4 x Wm=4)
  layer<1, 1,  4,  4, false, 3>(Bf + 557056, bl4, sB1, nullptr, outg, pair0,
                                wave & 3, (wave >> 2) * 16, lane);
}

extern "C" void kernel_launch(void* const* d_in, const int* in_sizes, int n_in,
                              void* d_out, int out_size, void* d_ws, size_t ws_size,
                              hipStream_t stream) {
  const float* x1  = (const float*)d_in[0];
  const float* x2  = (const float*)d_in[3];
  const float* W1  = (const float*)d_in[6];
  const float* b1  = (const float*)d_in[7];
  const float* W2  = (const float*)d_in[8];
  const float* b2  = (const float*)d_in[9];
  const float* W3  = (const float*)d_in[10];
  const float* b3  = (const float*)d_in[11];
  const float* Wl1 = (const float*)d_in[12];
  const float* bl1 = (const float*)d_in[13];
  const float* Wl2 = (const float*)d_in[14];
  const float* bl2 = (const float*)d_in[15];
  const float* Wl3 = (const float*)d_in[16];
  const float* bl3 = (const float*)d_in[17];
  const float* Wl4 = (const float*)d_in[18];
  const float* bl4 = (const float*)d_in[19];

  _Float16* Bf = (_Float16*)d_ws;   // 565248 halves = 1.13 MB

  PrepArgsV15 pa;
  pa.in[0] = W2;  pa.in[1] = W3;  pa.in[2] = Wl1;
  pa.in[3] = Wl2; pa.in[4] = Wl3; pa.in[5] = Wl4;

  v15_prep<<<dim3(276), dim3(256), 0, stream>>>(pa, Bf);
  v15_mega<<<dim3(250), dim3(1024), 0, stream>>>(x1, x2, W1, b1, Bf,
                                                 b2, b3, bl1, bl2, bl3, bl4,
                                                 (float*)d_out);
}

// Round 3
// 115.672 us; speedup vs baseline: 1.0725x; 1.0219x over previous
//
#include <hip/hip_runtime.h>

// GraphPairClassifier v16: v15 + transposed-MFMA epilogue packing.
//   Core change: compute D^T = W^T * Act^T by SWAPPING mfma operands
//   (a_op = weight frag, b_op = activation frag). The A/B fragment index
//   structures of 16x16x32 are identical (dim=lane&15, k=quad*8+j), so the
//   prep buffer and the LDS activation-read pattern are UNCHANGED; only the
//   C-layout transposes: lane&15 = m-row, regs = 4 CONSECUTIVE n-cols.
//   Epilogue: float4 bias + packed 8B ds_write_b64 (4x fewer LDS writes;
//   was ~1800 scalar u16 wave-writes ~ 10k cyc/CU) and dwordx4 sigmoid
//   stores. Also: distance-3 B prefetch (4 slots), packed L1 writes.
//   250 blocks x 50 pairs x 1024 threads (16 waves = 4/SIMD), ping-pong LDS,
//   m-split on A-heavy layers (L2/L3/H2/H3) per v15.
// Dtypes: device inputs FP32 (bf16-quantized values => fp16 weights exact);
//   output FP32. absmax 3.9e-3 stable R6-R15.

typedef _Float16 half8 __attribute__((ext_vector_type(8)));
typedef _Float16 half4 __attribute__((ext_vector_type(4)));
typedef float floatx4 __attribute__((ext_vector_type(4)));

// -------- weight prep: fp32 [K,N] row-major -> fp16 16x16x32-fragment order -
// fragment f: lane=f&63, rem=f>>6, nt=rem%(N/16), kb=rem/(N/16);
//   n = nt*16+(lane&15), k = kb*32+(lane>>4)*8+j, j=0..7.
// Serves as the A-operand frag of W^T (same indexing by A/B layout symmetry).
struct PrepArgsV16 { const float* in[6]; };

__global__ __launch_bounds__(256) void v16_prep(PrepArgsV16 p, _Float16* Bf) {
  const int frags[6] = {8192, 8192, 32768, 16384, 4096, 1024};  // sz/8
  const int lgN[6]   = {8, 8, 9, 8, 7, 6};
  const int off[6]   = {0, 65536, 131072, 393216, 524288, 557056};
  int f = blockIdx.x * 256 + threadIdx.x;
  for (int i = 0; i < 6; ++i) {
    if (f < frags[i]) {
      int N = 1 << lgN[i];
      int lane = f & 63, rem = f >> 6;
      int nt = rem & ((N >> 4) - 1);
      int kb = rem >> (lgN[i] - 4);
      int n = nt * 16 + (lane & 15);
      int k0 = kb * 32 + (lane >> 4) * 8;
      const float* src = p.in[i] + (size_t)k0 * N + n;
      half8 v;
#pragma unroll
      for (int j = 0; j < 8; ++j) v[j] = (_Float16)src[(size_t)j * N];
      *(half8*)(Bf + off[i] + (size_t)f * 8) = v;   // exact: bf16-valued
      return;
    }
    f -= frags[i];
  }
}

// -------- generic ping-pong layer, distance-3 B prefetch, D^T epilogue -----
// MT m-tiles (16 rows from m0), NT n-tiles at n-slot nw, TNT = N/16 total
// n-tiles, KB k-steps of 32. ENC_IN: srcA stride 264 halves; else 520.
// OUT_MODE 0: relu->encode(dst); 1: relu->head concat(dst); 2: relu->head(dst);
//          3: sigmoid->global fp32 (rows r<50 only).
// mfma(a_op=W frag, b_op=Act frag) => D^T: r = m0+mt*16+(lane&15),
//   c = n0+nt*16+quad*4+reg (4 consecutive cols per lane -> packed writes).
// NO trailing barrier here — caller syncs (calls may be wave-divergent).
template<int MT, int NT, int TNT, int KB, bool ENC_IN, int OUT_MODE>
__device__ __forceinline__ void layer(
    const _Float16* __restrict__ Bf, const float* __restrict__ bias,
    const _Float16* __restrict__ srcA, _Float16* dstA, float* __restrict__ outg,
    int pair0, int nw, int m0, int lane) {
  const int quad = lane >> 4, lr = lane & 15;
  const int n0 = nw * (NT * 16);
  const int STRIDE = ENC_IN ? 264 : 520;
  const _Float16* bp = Bf + ((size_t)(nw * NT) * 64 + lane) * 8;

  floatx4 acc[MT][NT];
#pragma unroll
  for (int mt = 0; mt < MT; ++mt)
#pragma unroll
    for (int nt = 0; nt < NT; ++nt)
      acc[mt][nt] = (floatx4){0.f, 0.f, 0.f, 0.f};

  half8 bbuf[4][NT];
#pragma unroll
  for (int s = 0; s < 3; ++s)
#pragma unroll
    for (int nt = 0; nt < NT; ++nt)
      bbuf[s][nt] = *(const half8*)(bp + (size_t)s * (TNT * 512) + nt * 512);

#pragma unroll
  for (int kb = 0; kb < KB; ++kb) {
    const int cur = kb & 3;
    half8 av[MT];
#pragma unroll
    for (int mt = 0; mt < MT; ++mt)
      av[mt] = *(const half8*)(srcA + (m0 + mt * 16 + lr) * STRIDE + kb * 32 + quad * 8);
#pragma unroll
    for (int nt = 0; nt < NT; ++nt)
#pragma unroll
      for (int mt = 0; mt < MT; ++mt)
        acc[mt][nt] = __builtin_amdgcn_mfma_f32_16x16x32_f16(bbuf[cur][nt], av[mt], acc[mt][nt], 0, 0, 0);
    if (kb + 3 < KB) {
      const int nxt = (kb + 3) & 3;
#pragma unroll
      for (int nt = 0; nt < NT; ++nt)
        bbuf[nxt][nt] = *(const half8*)(bp + (size_t)(kb + 3) * (TNT * 512) + nt * 512);
    }
  }

  // epilogue straight after own MFMAs: dst buffer != src buffer (no WAR)
#pragma unroll
  for (int nt = 0; nt < NT; ++nt) {
    const int c0 = n0 + nt * 16 + quad * 4;
    const floatx4 bv = *(const floatx4*)(bias + c0);
#pragma unroll
    for (int mt = 0; mt < MT; ++mt) {
      const int r = m0 + mt * 16 + lr;
      floatx4 v = acc[mt][nt] + bv;
      if (OUT_MODE <= 2) {
        half4 h;
#pragma unroll
        for (int reg = 0; reg < 4; ++reg) h[reg] = (_Float16)fmaxf(v[reg], 0.f);
        int a;
        if (OUT_MODE == 0)      a = r * 264 + c0;                         // encode
        else if (OUT_MODE == 1) a = (r >> 1) * 520 + (r & 1) * 256 + c0;  // concat
        else                    a = r * 520 + c0;                         // head
        *(half4*)(dstA + a) = h;                                          // 8B write
      } else {
        if (r < 50) {
          floatx4 o;
#pragma unroll
          for (int reg = 0; reg < 4; ++reg) o[reg] = 1.0f / (1.0f + expf(-v[reg]));
          *(floatx4*)(outg + (size_t)(pair0 + r) * 64 + c0) = o;          // 16B store
        }
      }
    }
  }
}

// -------- megakernel: 50 pairs (100 side rows, pad 112) per 1024-thr block --
__global__ __launch_bounds__(1024) void v16_mega(
    const float* __restrict__ x1, const float* __restrict__ x2,
    const float* __restrict__ W1, const float* __restrict__ b1,
    const _Float16* __restrict__ Bf,
    const float* __restrict__ b2, const float* __restrict__ b3,
    const float* __restrict__ bl1, const float* __restrict__ bl2,
    const float* __restrict__ bl3, const float* __restrict__ bl4,
    float* __restrict__ outg) {
  // ping-pong buffers: encode [112][264]=29568 halves; head [64][520]=33280
  __shared__ _Float16 sB0[33280];
  __shared__ _Float16 sB1[33280];
  __shared__ float sM[112][3];

  int tid = threadIdx.x;
  int wave = tid >> 6, lane = tid & 63;
  int pair0 = blockIdx.x * 50;

  // Phase -1: guarantee sB0 is fully finite after L1. L1 writes encode halves
  // [0,29568); H1 later reads head rows 56..63 = halves [29120,33280). Zero
  // the never-written tail [29568,33280) plus overlap (cheap, one pass).
  for (int i = tid; i < 2080; i += 1024) ((float*)sB0)[14560 + i] = 0.f;

  // Phase 0: per-side-row mean of the 4 node coords (100 real rows, 12 pad)
  if (tid < 112) {
    int r = tid;
    float a0 = 0.f, a1 = 0.f, a2 = 0.f;
    if (r < 100) {
      int g = pair0 + (r >> 1);                    // always < 12500
      const float* q = ((r & 1) ? x2 : x1) + (size_t)g * 12;
      a0 = 0.25f * (q[0] + q[3] + q[6] + q[9]);
      a1 = 0.25f * (q[1] + q[4] + q[7] + q[10]);
      a2 = 0.25f * (q[2] + q[5] + q[8] + q[11]);
    }
    sM[r][0] = a0; sM[r][1] = a1; sM[r][2] = a2;
  }
  __syncthreads();

  // Phase 1: L1 (3 -> 256), fp32 VALU, packed half4 writes into sB0.
  // Thread -> (4-col group, row residue): 64 col-groups x 16 row-residues.
  {
    int c4 = (tid & 63) * 4;          // 0..252
    int rb = tid >> 6;                // 0..15
    floatx4 w0 = *(const floatx4*)(W1 + c4);
    floatx4 w1 = *(const floatx4*)(W1 + 256 + c4);
    floatx4 w2 = *(const floatx4*)(W1 + 512 + c4);
    floatx4 bb = *(const floatx4*)(b1 + c4);
    for (int r = rb; r < 112; r += 16) {
      float s0 = sM[r][0], s1 = sM[r][1], s2 = sM[r][2];
      half4 h;
#pragma unroll
      for (int j = 0; j < 4; ++j) {
        float v = fmaxf(s0 * w0[j] + s1 * w1[j] + s2 * w2[j] + bb[j], 0.f);
        h[j] = (_Float16)v;
      }
      *(half4*)(sB0 + r * 264 + c4) = h;
    }
  }
  __syncthreads();

  // L2: [112x256]@[256x256] relu, sB0->sB1   (Wn=8 x Wm=2: rows 0..63 / 64..111)
  if (wave < 8) layer<4, 2, 16,  8, true,  0>(Bf + 0,      b2,  sB0, sB1, nullptr, pair0, wave,     0,  lane);
  else          layer<3, 2, 16,  8, true,  0>(Bf + 0,      b2,  sB0, sB1, nullptr, pair0, wave - 8, 64, lane);
  __syncthreads();
  // L3: [112x256]@[256x256] relu, sB1->sB0 (concat head layout)
  if (wave < 8) layer<4, 2, 16,  8, true,  1>(Bf + 65536,  b3,  sB1, sB0, nullptr, pair0, wave,     0,  lane);
  else          layer<3, 2, 16,  8, true,  1>(Bf + 65536,  b3,  sB1, sB0, nullptr, pair0, wave - 8, 64, lane);
  __syncthreads();
  // H1: [64x512]@[512x512] relu, sB0->sB1    (Wn=16 x NT=2; B-heavy, no m-split)
  layer<4, 2, 32, 16, false, 2>(Bf + 131072, bl1, sB0, sB1, nullptr, pair0, wave, 0, lane);
  __syncthreads();
  // H2: [64x512]@[512x256] relu, sB1->sB0    (Wn=8 x Wm=2: rows 0..31 / 32..63)
  if (wave < 8) layer<2, 2, 16, 16, false, 2>(Bf + 393216, bl2, sB1, sB0, nullptr, pair0, wave,     0,  lane);
  else          layer<2, 2, 16, 16, false, 2>(Bf + 393216, bl2, sB1, sB0, nullptr, pair0, wave - 8, 32, lane);
  __syncthreads();
  // H3: [64x256]@[256x128] relu, sB0->sB1    (Wn=8 x Wm=2)
  layer<2, 1,  8,  8, false, 2>(Bf + 524288, bl3, sB0, sB1, nullptr, pair0,
                                wave & 7, (wave >> 3) * 32, lane);
  __syncthreads();
  // H4: [64x128]@[128x64] sigmoid -> global  (Wn=4 x Wm=4)
  layer<1, 1,  4,  4, false, 3>(Bf + 557056, bl4, sB1, nullptr, outg, pair0,
                                wave & 3, (wave >> 2) * 16, lane);
}

extern "C" void kernel_launch(void* const* d_in, const int* in_sizes, int n_in,
                              void* d_out, int out_size, void* d_ws, size_t ws_size,
                              hipStream_t stream) {
  const float* x1  = (const float*)d_in[0];
  const float* x2  = (const float*)d_in[3];
  const float* W1  = (const float*)d_in[6];
  const float* b1  = (const float*)d_in[7];
  const float* W2  = (const float*)d_in[8];
  const float* b2  = (const float*)d_in[9];
  const float* W3  = (const float*)d_in[10];
  const float* b3  = (const float*)d_in[11];
  const float* Wl1 = (const float*)d_in[12];
  const float* bl1 = (const float*)d_in[13];
  const float* Wl2 = (const float*)d_in[14];
  const float* bl2 = (const float*)d_in[15];
  const float* Wl3 = (const float*)d_in[16];
  const float* bl3 = (const float*)d_in[17];
  const float* Wl4 = (const float*)d_in[18];
  const float* bl4 = (const float*)d_in[19];

  _Float16* Bf = (_Float16*)d_ws;   // 565248 halves = 1.13 MB

  PrepArgsV16 pa;
  pa.in[0] = W2;  pa.in[1] = W3;  pa.in[2] = Wl1;
  pa.in[3] = Wl2; pa.in[4] = Wl3; pa.in[5] = Wl4;

  v16_prep<<<dim3(276), dim3(256), 0, stream>>>(pa, Bf);
  v16_mega<<<dim3(250), dim3(1024), 0, stream>>>(x1, x2, W1, b1, Bf,
                                                 b2, b3, bl1, bl2, bl3, bl4,
                                                 (float*)d_out);
}